// Round 10
// baseline (4996.453 us; speedup 1.0000x reference)
//
#include <hip/hip_runtime.h>
#include <cmath>

typedef unsigned int u32;
typedef unsigned long long u64;

#define TCAND 4768
#define RTOT  261888
#define NW    75
#define NROWS 4800
#define NEGV  -1e9f

__device__ __forceinline__ u32 fkey(float s){
  u32 u = __float_as_uint(s);
  return u ^ ((u >> 31) ? 0xFFFFFFFFu : 0x80000000u);
}

// async global->LDS (lds base wave-uniform; HW adds lane*size; global addr per-lane)
__device__ __forceinline__ void gload_lds16(const float* g, float* l){
  __builtin_amdgcn_global_load_lds((const __attribute__((address_space(1))) void*)g,
                                   (__attribute__((address_space(3))) void*)l, 16, 0, 0);
}
__device__ __forceinline__ void gload_lds4(const float* g, float* l){
  __builtin_amdgcn_global_load_lds((const __attribute__((address_space(1))) void*)g,
                                   (__attribute__((address_space(3))) void*)l, 4, 0, 0);
}

// -------- descending bitonic sort of u64 in LDS (N power of two) --------
__device__ void bitonic_desc(u64* a, int N, int t, int nt){
  for (int len = 2; len <= N; len <<= 1){
    for (int inc = len >> 1; inc > 0; inc >>= 1){
      __syncthreads();
      for (int idx = t; idx < (N >> 1); idx += nt){
        int i = 2*idx - (idx & (inc - 1));
        int j = i + inc;
        u64 x = a[i], y = a[j];
        bool descR = ((i & len) == 0);
        bool sw = descR ? (x < y) : (x > y);
        if (sw){ a[i] = y; a[j] = x; }
      }
    }
  }
  __syncthreads();
}

// -------- kernel 0: weights -> w_r2[ic][tap][oc] (oc fastest) + zero page --------
__global__ void wtrans(const float* __restrict__ w, float* __restrict__ w_r2,
                       float* __restrict__ zbuf){
  if (blockIdx.x == 0 && threadIdx.x < 16) zbuf[threadIdx.x] = 0.f;
  int idx = blockIdx.x * 256 + threadIdx.x;
  if (idx >= 589824) return;
  int ic = idx / 2304;
  int f  = idx - ic * 2304;
  int tap = f >> 8;
  int oc  = f & 255;
  w_r2[idx] = w[oc * 2304 + ic * 9 + tap];
}

// -------- fused conv3x3 + heads + decode; 4oc x 16px per thread, 512 thr --------
// Tile = 16x8 px; wave u owns px rows 2u,2u+1 x all 256 oc (lane=ocg, oc=4ocg+k).
// Each 16B wk read feeds 64 FMAs (2x round 9) -> LDS weight traffic per FMA halved.
// 3-buffer pipeline, counted vmcnt, WAIT-THEN-BARRIER (verified R7 ordering).
// Per-accumulator fmaf chain (ic asc, ky, kx) and head 16-chain + xor-butterfly
// tree identical to the verified R5/R7/R9 kernels -> bit-exact (absmax 0.0).
template<int H, int STRIDEV, int ASIZE, int FOFF>
__device__ __forceinline__ void conv_level(
    int rel, const float* __restrict__ feat, const float* __restrict__ w_r2,
    const float* __restrict__ zbuf,
    const float* __restrict__ b_inter, const float* __restrict__ w_logits,
    const float* __restrict__ b_logits, const float* __restrict__ w_reg,
    const float* __restrict__ b_reg, const int* __restrict__ imgp,
    float* __restrict__ score_base, float* __restrict__ box_base,
    float* lds_w, float* lds_x, float* sbuf)
{
  constexpr int W = H;
  constexpr int TXC = W / 8;
  constexpr int TYR = H / 16;
  constexpr int TILES = TXC * TYR;
  const int t = threadIdx.x;
  const int img = rel / TILES;
  const int tile = rel - img * TILES;
  const int x0 = (tile % TXC) << 3;
  const int y0 = (tile / TXC) << 4;
  const int lane = t & 63;
  const int ocg = lane;          // oc = ocg*4 + k
  const int u = t >> 6;          // wave id; px rows 2u, 2u+1
  const int q = u;

  const size_t fb = (size_t)img * 256 * H * W;
  const size_t plane = (size_t)H * W;

  // x staging: waves 1..4 cover the 18x12 patch (216 cells; pads/OOB -> zero page)
  const float* xsrc = zbuf;
  size_t xstep = 0;
  if (q >= 1 && q <= 4){
    int cell = (q - 1) * 64 + lane;
    int xr = cell / 12, xc = cell - xr * 12;
    int gy = y0 + xr - 1, gx = x0 + xc - 1;
    bool ok = (cell < 216) && (xc < 10) && gy >= 0 && gy < H && gx >= 0 && gx < W;
    if (ok){ xsrc = feat + fb + (size_t)gy * W + gx; xstep = plane; }
  }

  float acc[64];
  #pragma unroll
  for (int j = 0; j < 64; j++) acc[j] = 0.f;

  // stage ic into buffer sb: wave q weight chunk q (wave 0 also tail chunk 8),
  // waves 1..4 stage the x patch
  #define STAGE(icv, sb) do { \
    const float* wg_ = w_r2 + (size_t)(icv) * 2304; \
    float* wl_ = lds_w + (sb) * 2304; \
    gload_lds16(wg_ + q * 256 + lane * 4, wl_ + q * 256); \
    if (q == 0) gload_lds16(wg_ + 2048 + lane * 4, wl_ + 2048); \
    if (q >= 1 && q <= 4) gload_lds4(xsrc + (size_t)(icv) * xstep, \
                                     lds_x + (sb) * 256 + (q - 1) * 64); \
  } while (0)

  STAGE(0, 0);
  STAGE(1, 1);

  int cur = 0;
  #pragma unroll 1
  for (int ic = 0; ic < 256; ++ic){
    // barrier1: all waves finished compute(ic-1) -> safe to overwrite buf (ic+2)%3
    __builtin_amdgcn_s_barrier();
    __builtin_amdgcn_sched_barrier(0);
    if (ic < 254){
      int sb = cur + 2; if (sb >= 3) sb -= 3;
      STAGE(ic + 2, sb);
    }
    __builtin_amdgcn_sched_barrier(0);
    // own wait: batch ic fully landed (batches ic+1, ic+2 may stay in flight)
    if (ic < 254){
      if (q <= 4) asm volatile("s_waitcnt vmcnt(4)" ::: "memory");
      else        asm volatile("s_waitcnt vmcnt(2)" ::: "memory");
    } else if (ic == 254){
      if (q <= 4) asm volatile("s_waitcnt vmcnt(2)" ::: "memory");
      else        asm volatile("s_waitcnt vmcnt(1)" ::: "memory");
    } else {
      asm volatile("s_waitcnt vmcnt(0)" ::: "memory");
    }
    __builtin_amdgcn_sched_barrier(0);
    // barrier2: every wave's wait precedes -> batch ic LDS writes visible to all
    __builtin_amdgcn_s_barrier();
    __builtin_amdgcn_sched_barrier(0);

    const float* wbuf = lds_w + cur * 2304;
    const float* xbuf = lds_x + cur * 256;
    #pragma unroll 1
    for (int ky = 0; ky < 3; ky++){
      float xr0[10], xr1[10];
      {
        const float* xp0 = xbuf + (2 * u + ky) * 12;
        *(float4*)&xr0[0] = *(const float4*)xp0;
        *(float4*)&xr0[4] = *(const float4*)(xp0 + 4);
        *(float2*)&xr0[8] = *(const float2*)(xp0 + 8);
        const float* xp1 = xp0 + 12;
        *(float4*)&xr1[0] = *(const float4*)xp1;
        *(float4*)&xr1[4] = *(const float4*)(xp1 + 4);
        *(float2*)&xr1[8] = *(const float2*)(xp1 + 8);
      }
      #pragma unroll
      for (int kx = 0; kx < 3; kx++){
        float wk[4];
        *(float4*)&wk[0] = *(const float4*)(wbuf + (ky * 3 + kx) * 256 + ocg * 4);
        #pragma unroll
        for (int k = 0; k < 4; k++){
          #pragma unroll
          for (int c = 0; c < 16; c++){
            float xv = (c < 8) ? xr0[(c & 7) + kx] : xr1[(c & 7) + kx];
            acc[k * 16 + c] = __builtin_fmaf(wk[k], xv, acc[k * 16 + c]);
          }
        }
      }
    }
    cur = cur + 1; if (cur == 3) cur = 0;
  }
  #undef STAGE

  // bias + relu in place (oc = ocg*4 + k)
  {
    float bb[4];
    *(float4*)&bb[0] = *(const float4*)(b_inter + ocg * 4);
    #pragma unroll
    for (int k = 0; k < 4; k++)
      #pragma unroll
      for (int c = 0; c < 16; c++)
        acc[k * 16 + c] = fmaxf(acc[k * 16 + c] + bb[k], 0.f);
  }

  // heads: exact 16-chain + xor butterfly tree (bit-exact, verified)
  const int grp = ocg & 60;
  #pragma unroll 1
  for (int o = 0; o < 15; o++){
    const float* whp = (o < 3) ? (w_logits + o * 256) : (w_reg + (o - 3) * 256);
    float wh4[4];
    *(float4*)&wh4[0] = *(const float4*)(whp + ocg * 4);
    #pragma unroll
    for (int c = 0; c < 16; c++){
      float t1 = 0.f;
      #pragma unroll
      for (int k = 0; k < 4; k++) t1 = __builtin_fmaf(wh4[k], acc[k * 16 + c], t1);
      float b1 = __shfl(t1, grp);
      float t2 = b1;
      #pragma unroll
      for (int k = 0; k < 4; k++) t2 = __builtin_fmaf(wh4[k], acc[k * 16 + c], t2);
      float b2 = __shfl(t2, grp + 1);
      float t3 = b2;
      #pragma unroll
      for (int k = 0; k < 4; k++) t3 = __builtin_fmaf(wh4[k], acc[k * 16 + c], t3);
      float b3 = __shfl(t3, grp + 2);
      float t4 = b3;
      #pragma unroll
      for (int k = 0; k < 4; k++) t4 = __builtin_fmaf(wh4[k], acc[k * 16 + c], t4);
      float v = t4 + __shfl_xor(t4, 4);
      v = v + __shfl_xor(v, 8);
      v = v + __shfl_xor(v, 16);
      v = v + __shfl_xor(v, 32);
      if (ocg == 3) sbuf[(u * 16 + c) * 16 + o] = v;
    }
  }
  __syncthreads();

  // decode (verbatim verified arithmetic); 128 px x 3 anchors
  if (t < 384){
    int a = t >> 7; int px = t & 127;
    int rr = px >> 3, cc = px & 7;
    int y = y0 + rr, x = x0 + cc;
    float img_f = (float)(*imgp);
    float sc = sbuf[px * 16 + a] + b_logits[a];
    float d0 = sbuf[px * 16 + 3 + a * 4 + 0] + b_reg[a * 4 + 0];
    float d1 = sbuf[px * 16 + 3 + a * 4 + 1] + b_reg[a * 4 + 1];
    float d2 = sbuf[px * 16 + 3 + a * 4 + 2] + b_reg[a * 4 + 2];
    float d3 = sbuf[px * 16 + 3 + a * 4 + 3] + b_reg[a * 4 + 3];
    double ar = (a == 0) ? 0.5 : ((a == 1) ? 1.0 : 2.0);
    double area_d = (double)ASIZE * (double)ASIZE;
    double wd = sqrt(area_d / ar);
    double hd = ar * wd;
    float bx1 = (float)(-wd * 0.5), by1 = (float)(-hd * 0.5);
    float bx2 = (float)( wd * 0.5), by2 = (float)( hd * 0.5);
    float sx = (float)(x * STRIDEV), sy = (float)(y * STRIDEV);
    float ax1 = sx + bx1, ay1 = sy + by1, ax2 = sx + bx2, ay2 = sy + by2;
    float aw = __fsub_rn(ax2, ax1), ah = __fsub_rn(ay2, ay1);
    float acx = __fadd_rn(ax1, __fmul_rn(0.5f, aw));
    float acy = __fadd_rn(ay1, __fmul_rn(0.5f, ah));
    const float CLAMP = (float)4.135166556742356;
    float dwv = fminf(d2, CLAMP), dhv = fminf(d3, CLAMP);
    float pcx = __fadd_rn(__fmul_rn(d0, aw), acx);
    float pcy = __fadd_rn(__fmul_rn(d1, ah), acy);
    float pw = __fmul_rn((float)exp((double)dwv), aw);
    float ph = __fmul_rn((float)exp((double)dhv), ah);
    float hx = __fmul_rn(0.5f, pw), hy = __fmul_rn(0.5f, ph);
    float X1 = __fsub_rn(pcx, hx), Y1 = __fsub_rn(pcy, hy);
    float X2 = __fadd_rn(pcx, hx), Y2 = __fadd_rn(pcy, hy);
    X1 = fminf(fmaxf(X1, 0.f), img_f); Y1 = fminf(fmaxf(Y1, 0.f), img_f);
    X2 = fminf(fmaxf(X2, 0.f), img_f); Y2 = fminf(fmaxf(Y2, 0.f), img_f);
    int gi = (y * W + x) * 3 + a;
    size_t oidx = (size_t)img * RTOT + FOFF + gi;
    score_base[oidx] = sc;
    ((float4*)box_base)[oidx] = make_float4(X1, Y1, X2, Y2);
  }
}

__global__ __launch_bounds__(512, 4) void conv_all(
    const float* __restrict__ f2, const float* __restrict__ f3,
    const float* __restrict__ f4, const float* __restrict__ f5,
    const float* __restrict__ f6, const float* __restrict__ w_r2,
    const float* __restrict__ zbuf,
    const float* __restrict__ b_inter, const float* __restrict__ w_logits,
    const float* __restrict__ b_logits, const float* __restrict__ w_reg,
    const float* __restrict__ b_reg, const int* __restrict__ imgp,
    float* __restrict__ score_base, float* __restrict__ box_base)
{
  __shared__ float lds_w[3 * 2304];
  __shared__ float lds_x[3 * 256];
  __shared__ float sbuf[128 * 16];
  const int bid = blockIdx.x;
  if (bid < 1024)
    conv_level<256, 4, 32, 0>(bid, f2, w_r2, zbuf, b_inter, w_logits, b_logits, w_reg,
                              b_reg, imgp, score_base, box_base, lds_w, lds_x, sbuf);
  else if (bid < 1280)
    conv_level<128, 8, 64, 196608>(bid - 1024, f3, w_r2, zbuf, b_inter, w_logits, b_logits,
                                   w_reg, b_reg, imgp, score_base, box_base, lds_w, lds_x, sbuf);
  else if (bid < 1344)
    conv_level<64, 16, 128, 245760>(bid - 1280, f4, w_r2, zbuf, b_inter, w_logits, b_logits,
                                    w_reg, b_reg, imgp, score_base, box_base, lds_w, lds_x, sbuf);
  else if (bid < 1360)
    conv_level<32, 32, 256, 258048>(bid - 1344, f5, w_r2, zbuf, b_inter, w_logits, b_logits,
                                    w_reg, b_reg, imgp, score_base, box_base, lds_w, lds_x, sbuf);
  else
    conv_level<16, 64, 512, 261120>(bid - 1360, f6, w_r2, zbuf, b_inter, w_logits, b_logits,
                                    w_reg, b_reg, imgp, score_base, box_base, lds_w, lds_x, sbuf);
}

// -------- kernel 2: per (level,image) exact top-k (radix select + bitonic) --------
__global__ __launch_bounds__(1024) void topk_lvl(
    const float* __restrict__ score_base, const float* __restrict__ box_base,
    float* __restrict__ cs, float* __restrict__ cb, int* __restrict__ clvl)
{
  const int lvl = blockIdx.x, b = blockIdx.y;
  const int Rtab[5] = {196608, 49152, 12288, 3072, 768};
  const int Ktab[5] = {1000, 1000, 1000, 1000, 768};
  const int Ftab[5] = {0, 196608, 245760, 258048, 261120};
  const int Ctab[5] = {0, 1000, 2000, 3000, 4000};
  const int R = Rtab[lvl], kk = Ktab[lvl], foff = Ftab[lvl], coff = Ctab[lvl];
  const float* sc = score_base + (size_t)b * RTOT + foff;
  const int t = threadIdx.x;
  __shared__ u32 hist[256];
  __shared__ u32 sh_prefix, sh_r;
  __shared__ u32 cgt, ceq;
  __shared__ u64 sel[1024];
  __shared__ u64 eqb[1024];
  if (t == 0){ sh_prefix = 0u; sh_r = (u32)kk; }
  __syncthreads();
  for (int pass = 0; pass < 4; ++pass){
    if (t < 256) hist[t] = 0u;
    __syncthreads();
    u32 prefix = sh_prefix;
    int shift = 24 - 8 * pass;
    u32 maskHi = (pass == 0) ? 0u : (0xFFFFFFFFu << (shift + 8));
    for (int i = t; i < R; i += 1024){
      u32 key = fkey(sc[i]);
      if ((key & maskHi) == prefix) atomicAdd(&hist[(key >> shift) & 255u], 1u);
    }
    __syncthreads();
    if (t == 0){
      u32 r = sh_r; u32 run = 0; int chosen = 255;
      for (int bv = 255; bv >= 0; --bv){
        u32 c = hist[bv];
        if (run + c >= r){ chosen = bv; break; }
        run += c;
      }
      sh_prefix = prefix | ((u32)chosen << shift);
      sh_r = r - run;
    }
    __syncthreads();
  }
  const u32 Tkey = sh_prefix; const u32 need_eq = sh_r;
  if (t == 0){ cgt = 0u; ceq = 0u; }
  __syncthreads();
  for (int i = t; i < R; i += 1024){
    u32 key = fkey(sc[i]);
    if (key > Tkey){
      u32 p = atomicAdd(&cgt, 1u);
      sel[p] = (((u64)key) << 32) | (u64)(0xFFFFFFFFu - (u32)i);
    } else if (key == Tkey){
      u32 e = atomicAdd(&ceq, 1u);
      if (e < 1024u) eqb[e] = (u64)(0xFFFFFFFFu - (u32)i);
    }
  }
  __syncthreads();
  u32 nGt = cgt; u32 nEq = ceq > 1024u ? 1024u : ceq;
  if ((u32)t >= nEq) eqb[t] = 0ull;
  __syncthreads();
  bitonic_desc(eqb, 1024, t, 1024);
  if ((u32)t < need_eq) sel[nGt + t] = (((u64)Tkey) << 32) | (eqb[t] & 0xFFFFFFFFull);
  if (t >= kk) sel[t] = 0ull;
  __syncthreads();
  bitonic_desc(sel, 1024, t, 1024);
  if (t < kk){
    u64 v = sel[t];
    u32 i = 0xFFFFFFFFu - (u32)(v & 0xFFFFFFFFull);
    int dst = b * TCAND + coff + t;
    cs[dst] = sc[i];
    ((float4*)cb)[dst] = ((const float4*)box_base)[(size_t)b * RTOT + foff + i];
    clvl[dst] = lvl;
  }
}

// -------- kernel 3: per-image global stable sort + NMS prep --------
__global__ __launch_bounds__(1024) void gsort(
    const float* __restrict__ cs, const float* __restrict__ cb, const int* __restrict__ clvl,
    const int* __restrict__ imgp,
    float* __restrict__ s_score, float* __restrict__ s_box, float* __restrict__ obox,
    float* __restrict__ area, int* __restrict__ validarr)
{
  const int b = blockIdx.x, t = threadIdx.x;
  __shared__ u64 arr[8192];
  for (int i = t; i < 8192; i += 1024){
    u64 v = 0ull;
    if (i < TCAND){
      u32 key = fkey(cs[b * TCAND + i]);
      v = (((u64)key) << 32) | (u64)(0xFFFFFFFFu - (u32)i);
    }
    arr[i] = v;
  }
  __syncthreads();
  bitonic_desc(arr, 8192, t, 1024);
  const float img = (float)(*imgp);
  const float off1 = img + 1.0f;
  for (int s = t; s < TCAND; s += 1024){
    u32 ci = 0xFFFFFFFFu - (u32)(arr[s] & 0xFFFFFFFFull);
    int src = b * TCAND + (int)ci;
    int dst = b * TCAND + s;
    float scv = cs[src];
    float4 bx = ((const float4*)cb)[src];
    s_score[dst] = scv;
    ((float4*)s_box)[dst] = bx;
    float lv = (float)clvl[src];
    float tt = __fmul_rn(lv, off1);
    float o0 = __fadd_rn(bx.x, tt), o1 = __fadd_rn(bx.y, tt);
    float o2 = __fadd_rn(bx.z, tt), o3 = __fadd_rn(bx.w, tt);
    ((float4*)obox)[dst] = make_float4(o0, o1, o2, o3);
    area[dst] = __fmul_rn(__fsub_rn(o2, o0), __fsub_rn(o3, o1));
    validarr[dst] = (bx.z > bx.x && bx.w > bx.y) ? 1 : 0;
  }
}

// -------- kernel 4: suppression bit-matrix (j>i, IoU>0.7) --------
__global__ void iou_mat(const float* __restrict__ obox, const float* __restrict__ area,
                        u64* __restrict__ supp)
{
  const int b = blockIdx.y;
  int wid = blockIdx.x * 256 + threadIdx.x;
  const int total = TCAND * NW;
  if (wid >= total) return;
  int i = wid / NW, w = wid - i * NW;
  float4 bi = ((const float4*)obox)[b * TCAND + i];
  float ai = area[b * TCAND + i];
  u64 bits = 0ull;
  int jbase = w << 6;
  for (int jj = 0; jj < 64; jj++){
    int j = jbase + jj;
    if (j >= TCAND) break;
    if (j <= i) continue;
    float4 bj = ((const float4*)obox)[b * TCAND + j];
    float xx1 = fmaxf(bi.x, bj.x), yy1 = fmaxf(bi.y, bj.y);
    float xx2 = fminf(bi.z, bj.z), yy2 = fminf(bi.w, bj.w);
    float iw = fmaxf(__fsub_rn(xx2, xx1), 0.f);
    float ih = fmaxf(__fsub_rn(yy2, yy1), 0.f);
    float inter = __fmul_rn(iw, ih);
    float uni = __fadd_rn(__fsub_rn(__fadd_rn(ai, area[b * TCAND + j]), inter), 1e-9f);
    float iou = inter / uni;
    if (iou > 0.7f) bits |= (1ull << jj);
  }
  supp[((size_t)b * NROWS + i) * NW + w] = bits;
}

// -------- kernel 5: exact greedy scan (1 wave per image, chunked) --------
__global__ __launch_bounds__(64) void nms_scan(const u64* __restrict__ supp,
                                               const int* __restrict__ validarr,
                                               u64* __restrict__ keep_out)
{
  const int b = blockIdx.x;
  const int lane = threadIdx.x;
  u64 rlo = 0ull, rhi = 0ull;
  for (int jj = 0; jj < 64; jj++){
    int i1 = (lane << 6) + jj;
    u64 bad1 = (i1 < TCAND) ? (validarr[b * TCAND + i1] ? 0ull : 1ull) : 1ull;
    rlo |= bad1 << jj;
    int i2 = ((lane + 64) << 6) + jj;
    u64 bad2 = (i2 < TCAND) ? (validarr[b * TCAND + i2] ? 0ull : 1ull) : 1ull;
    rhi |= bad2 << jj;
  }
  for (int c = 0; c < NW; c++){
    u64 rw = (c < 64) ? __shfl(rlo, c) : __shfl(rhi, c - 64);
    u64 diag = supp[((size_t)b * NROWS + (c << 6) + lane) * NW + c];
    for (int s = 0; s < 64; s++){
      if (!((rw >> s) & 1ull)) rw |= __shfl(diag, s);
    }
    if (c < 64){ if (lane == c) rlo = rw; }
    else       { if (lane == c - 64) rhi = rw; }
    u64 kept = ~rw;
    const u64* rowbase = supp + ((size_t)b * NROWS + (c << 6)) * NW;
    for (int s = 0; s < 64; s++){
      if ((kept >> s) & 1ull){
        rlo |= rowbase[(size_t)s * NW + lane];
        if (lane < 11) rhi |= rowbase[(size_t)s * NW + 64 + lane];
      }
    }
  }
  keep_out[b * 80 + lane] = ~rlo;
  if (lane < 11) keep_out[b * 80 + 64 + lane] = ~rhi;
}

// -------- kernel 6: stable compaction + emit [B,1000,5] --------
__global__ __launch_bounds__(1024) void emit(const u64* __restrict__ keep_out,
                                             const float* __restrict__ s_score,
                                             const float* __restrict__ s_box,
                                             float* __restrict__ out)
{
  const int b = blockIdx.x, t = threadIdx.x;
  __shared__ int part[1024];
  int f[5]; int base = t * 5; int lsum = 0;
  #pragma unroll
  for (int q = 0; q < 5; q++){
    int s = base + q; int kp = 0;
    if (s < TCAND) kp = (int)((keep_out[b * 80 + (s >> 6)] >> (s & 63)) & 1ull);
    f[q] = kp; lsum += kp;
  }
  part[t] = lsum;
  __syncthreads();
  for (int d = 1; d < 1024; d <<= 1){
    int addv = 0;
    if (t >= d) addv = part[t - d];
    __syncthreads();
    part[t] += addv;
    __syncthreads();
  }
  int K = part[1023];
  int kcnt = part[t] - lsum;
  #pragma unroll
  for (int q = 0; q < 5; q++){
    int s = base + q;
    if (s < TCAND){
      int pos = f[q] ? kcnt : (K + (s - kcnt));
      if (pos < 1000){
        float4 bx = ((const float4*)s_box)[b * TCAND + s];
        float scv = f[q] ? s_score[b * TCAND + s] : NEGV;
        float* o = out + ((size_t)b * 1000 + pos) * 5;
        o[0] = bx.x; o[1] = bx.y; o[2] = bx.z; o[3] = bx.w; o[4] = scv;
      }
      kcnt += f[q];
    }
  }
}

extern "C" void kernel_launch(void* const* d_in, const int* in_sizes, int n_in,
                              void* d_out, int out_size, void* d_ws, size_t ws_size,
                              hipStream_t stream)
{
  (void)in_sizes; (void)n_in; (void)out_size; (void)ws_size;
  const float* f2 = (const float*)d_in[0];
  const float* f3 = (const float*)d_in[1];
  const float* f4 = (const float*)d_in[2];
  const float* f5 = (const float*)d_in[3];
  const float* f6 = (const float*)d_in[4];
  const float* w_inter  = (const float*)d_in[5];
  const float* b_inter  = (const float*)d_in[6];
  const float* w_logits = (const float*)d_in[7];
  const float* b_logits = (const float*)d_in[8];
  const float* w_reg    = (const float*)d_in[9];
  const float* b_reg    = (const float*)d_in[10];
  const int*   imgp     = (const int*)d_in[11];

  char* ws = (char*)d_ws;
  float* w_r2       = (float*)(ws + 0);          // 2,359,296
  float* score_base = (float*)(ws + 2359296);    // 2,095,104
  float* box_base   = (float*)(ws + 4454400);    // 8,380,416
  float* cs         = (float*)(ws + 12834816);   // 38,144
  float* cb         = (float*)(ws + 12872960);   // 152,576
  int*   clvl       = (int*)  (ws + 13025536);   // 38,144
  float* s_score    = (float*)(ws + 13063680);   // 38,144
  float* s_box      = (float*)(ws + 13101824);   // 152,576
  float* obox       = (float*)(ws + 13254400);   // 152,576
  float* area       = (float*)(ws + 13406976);   // 38,144
  int*   validarr   = (int*)  (ws + 13445120);   // 38,144
  u64*   supp       = (u64*)  (ws + 13483264);   // 5,760,000
  u64*   keep_out   = (u64*)  (ws + 19243264);   // 1,280
  // zero page: aliases head of supp (re-zeroed by wtrans each launch; supp
  // is only written later in the same launch by iou_mat)
  float* zbuf       = (float*)(ws + 13483264);

  hipLaunchKernelGGL(wtrans, dim3((589824 + 255) / 256), dim3(256), 0, stream,
                     w_inter, w_r2, zbuf);

  hipLaunchKernelGGL(conv_all, dim3(1364), dim3(512), 0, stream,
                     f2, f3, f4, f5, f6, w_r2, zbuf, b_inter, w_logits, b_logits,
                     w_reg, b_reg, imgp, score_base, box_base);

  hipLaunchKernelGGL(topk_lvl, dim3(5, 2), dim3(1024), 0, stream,
                     score_base, box_base, cs, cb, clvl);
  hipLaunchKernelGGL(gsort, dim3(2), dim3(1024), 0, stream,
                     cs, cb, clvl, imgp, s_score, s_box, obox, area, validarr);
  hipLaunchKernelGGL(iou_mat, dim3((TCAND * NW + 255) / 256, 2), dim3(256), 0, stream,
                     obox, area, supp);
  hipLaunchKernelGGL(nms_scan, dim3(2), dim3(64), 0, stream, supp, validarr, keep_out);
  hipLaunchKernelGGL(emit, dim3(2), dim3(1024), 0, stream, keep_out, s_score, s_box,
                     (float*)d_out);
}

// Round 11
// 3997.867 us; speedup vs baseline: 1.2498x; 1.2498x over previous
//
#include <hip/hip_runtime.h>
#include <cmath>

typedef unsigned int u32;
typedef unsigned long long u64;

#define TCAND 4768
#define RTOT  261888
#define NW    75
#define NROWS 4800
#define NEGV  -1e9f

__device__ __forceinline__ u32 fkey(float s){
  u32 u = __float_as_uint(s);
  return u ^ ((u >> 31) ? 0xFFFFFFFFu : 0x80000000u);
}

// async global->LDS (lds base wave-uniform; HW adds lane*size; global addr per-lane)
__device__ __forceinline__ void gload_lds16(const float* g, float* l){
  __builtin_amdgcn_global_load_lds((const __attribute__((address_space(1))) void*)g,
                                   (__attribute__((address_space(3))) void*)l, 16, 0, 0);
}
__device__ __forceinline__ void gload_lds4(const float* g, float* l){
  __builtin_amdgcn_global_load_lds((const __attribute__((address_space(1))) void*)g,
                                   (__attribute__((address_space(3))) void*)l, 4, 0, 0);
}

// -------- descending bitonic sort of u64 in LDS (N power of two) --------
__device__ void bitonic_desc(u64* a, int N, int t, int nt){
  for (int len = 2; len <= N; len <<= 1){
    for (int inc = len >> 1; inc > 0; inc >>= 1){
      __syncthreads();
      for (int idx = t; idx < (N >> 1); idx += nt){
        int i = 2*idx - (idx & (inc - 1));
        int j = i + inc;
        u64 x = a[i], y = a[j];
        bool descR = ((i & len) == 0);
        bool sw = descR ? (x < y) : (x > y);
        if (sw){ a[i] = y; a[j] = x; }
      }
    }
  }
  __syncthreads();
}

// -------- kernel 0: weights -> w_r2[ic][tap][oc]; coalesced READ, scatter write --------
__global__ void wtrans(const float* __restrict__ w, float* __restrict__ w_r2,
                       float* __restrict__ zbuf){
  if (blockIdx.x == 0 && threadIdx.x < 16) zbuf[threadIdx.x] = 0.f;
  int idx = blockIdx.x * 256 + threadIdx.x;
  if (idx >= 589824) return;
  int oc = idx / 2304;
  int r  = idx - oc * 2304;
  int ic = r / 9;
  int tap = r - ic * 9;
  w_r2[ic * 2304 + tap * 256 + oc] = w[idx];
}

// -------- fused conv3x3 + heads + decode; 4oc x 8px per thread, 512 thr --------
// (verbatim round-9 kernel: BK=2, 2 LDS buffers, counted vmcnt, WAIT-THEN-BARRIER,
//  launch_bounds (512,4); verified spill-free, absmax 0.0, conv ~3.05 ms)
template<int H, int STRIDEV, int ASIZE, int FOFF>
__device__ __forceinline__ void conv_level(
    int rel, const float* __restrict__ feat, const float* __restrict__ w_r2,
    const float* __restrict__ zbuf,
    const float* __restrict__ b_inter, const float* __restrict__ w_logits,
    const float* __restrict__ b_logits, const float* __restrict__ w_reg,
    const float* __restrict__ b_reg, const int* __restrict__ imgp,
    float* __restrict__ score_base, float* __restrict__ box_base,
    float* lds_w, float* lds_x, float* sbuf)
{
  constexpr int W = H;
  constexpr int TX = H / 8;
  constexpr int TILES = TX * TX;
  const int t = threadIdx.x;
  const int img = rel / TILES;
  const int tile = rel - img * TILES;
  const int x0 = (tile % TX) << 3;
  const int y0 = (tile / TX) << 3;
  const int lane = t & 63;
  const int ocg = lane;          // oc = ocg*4 + k
  const int r = t >> 6;          // wave id = px row 0..7
  const int q = r;

  const size_t fb = (size_t)img * 256 * H * W;
  const size_t plane = (size_t)H * W;

  // per-lane x-cell source (waves 1,2 stage the 128-cell patch; pads/OOB -> zero page)
  const float* xsrc = zbuf;
  size_t xstep = 0;
  if (q == 1 || q == 2){
    int cell = (q - 1) * 64 + lane;
    int xr = cell / 12, xc = cell - xr * 12;
    int gy = y0 + xr - 1, gx = x0 + xc - 1;
    bool ok = (cell < 120) && (xc < 10) && gy >= 0 && gy < H && gx >= 0 && gx < W;
    if (ok){ xsrc = feat + fb + (size_t)gy * W + gx; xstep = plane; }
  }

  // weight chunk assignment for 18 chunks of 256 floats (2 ic = 4608 floats):
  const int c0 = 2 * q, c1 = 2 * q + 1;
  const int cex = (q == 0) ? 16 : ((q == 3) ? 17 : -1);

  float acc[32];
  #pragma unroll
  for (int j = 0; j < 32; j++) acc[j] = 0.f;

  #define STAGE(g_, sb) do { \
    const float* wg_ = w_r2 + (size_t)(g_) * 4608; \
    float* wl_ = lds_w + (sb) * 4608; \
    gload_lds16(wg_ + c0 * 256 + lane * 4, wl_ + c0 * 256); \
    gload_lds16(wg_ + c1 * 256 + lane * 4, wl_ + c1 * 256); \
    if (cex >= 0) gload_lds16(wg_ + cex * 256 + lane * 4, wl_ + cex * 256); \
    if (q == 1 || q == 2){ \
      gload_lds4(xsrc + (size_t)(2 * (g_)) * xstep, \
                 lds_x + (sb) * 256 + (q - 1) * 64); \
      gload_lds4(xsrc + (size_t)(2 * (g_) + 1) * xstep, \
                 lds_x + (sb) * 256 + 128 + (q - 1) * 64); \
    } \
  } while (0)

  STAGE(0, 0);

  int cur = 0;
  #pragma unroll 1
  for (int g = 0; g < 128; ++g){
    __builtin_amdgcn_s_barrier();
    __builtin_amdgcn_sched_barrier(0);
    if (g < 127){
      STAGE(g + 1, cur ^ 1);
    }
    __builtin_amdgcn_sched_barrier(0);
    if (g < 127){
      if (q == 1 || q == 2)      asm volatile("s_waitcnt vmcnt(4)" ::: "memory");
      else if (q == 0 || q == 3) asm volatile("s_waitcnt vmcnt(3)" ::: "memory");
      else                       asm volatile("s_waitcnt vmcnt(2)" ::: "memory");
    } else {
      asm volatile("s_waitcnt vmcnt(0)" ::: "memory");
    }
    __builtin_amdgcn_sched_barrier(0);
    __builtin_amdgcn_s_barrier();
    __builtin_amdgcn_sched_barrier(0);

    const float* wbuf = lds_w + cur * 4608;
    const float* xbuf = lds_x + cur * 256;
    #pragma unroll 1
    for (int icl = 0; icl < 2; icl++){
      const float* wsub = wbuf + icl * 2304;
      const float* xsub = xbuf + icl * 128;
      #pragma unroll
      for (int ky = 0; ky < 3; ky++){
        float xrow[10];
        {
          const float* xp = xsub + (r + ky) * 12;
          *(float4*)&xrow[0] = *(const float4*)xp;
          *(float4*)&xrow[4] = *(const float4*)(xp + 4);
          *(float2*)&xrow[8] = *(const float2*)(xp + 8);
        }
        #pragma unroll
        for (int kx = 0; kx < 3; kx++){
          const int tap = ky * 3 + kx;
          float wk[4];
          *(float4*)&wk[0] = *(const float4*)(wsub + tap * 256 + ocg * 4);
          #pragma unroll
          for (int k = 0; k < 4; k++){
            #pragma unroll
            for (int c = 0; c < 8; c++)
              acc[k * 8 + c] = __builtin_fmaf(wk[k], xrow[c + kx], acc[k * 8 + c]);
          }
        }
      }
    }
    cur ^= 1;
  }
  #undef STAGE

  // bias + relu in place (oc = ocg*4 + k)
  {
    float bb[4];
    *(float4*)&bb[0] = *(const float4*)(b_inter + ocg * 4);
    #pragma unroll
    for (int k = 0; k < 4; k++)
      #pragma unroll
      for (int c = 0; c < 8; c++)
        acc[k * 8 + c] = fmaxf(acc[k * 8 + c] + bb[k], 0.f);
  }

  // heads: exact 16-chain + xor butterfly tree (bit-exact, verified)
  const int grp = ocg & 60;
  #pragma unroll 1
  for (int o = 0; o < 15; o++){
    const float* whp = (o < 3) ? (w_logits + o * 256) : (w_reg + (o - 3) * 256);
    float wh4[4];
    *(float4*)&wh4[0] = *(const float4*)(whp + ocg * 4);
    float fin[8];
    #pragma unroll
    for (int c = 0; c < 8; c++){
      float t1 = 0.f;
      #pragma unroll
      for (int k = 0; k < 4; k++) t1 = __builtin_fmaf(wh4[k], acc[k * 8 + c], t1);
      float b1 = __shfl(t1, grp);
      float t2 = b1;
      #pragma unroll
      for (int k = 0; k < 4; k++) t2 = __builtin_fmaf(wh4[k], acc[k * 8 + c], t2);
      float b2 = __shfl(t2, grp + 1);
      float t3 = b2;
      #pragma unroll
      for (int k = 0; k < 4; k++) t3 = __builtin_fmaf(wh4[k], acc[k * 8 + c], t3);
      float b3 = __shfl(t3, grp + 2);
      float t4 = b3;
      #pragma unroll
      for (int k = 0; k < 4; k++) t4 = __builtin_fmaf(wh4[k], acc[k * 8 + c], t4);
      float v = t4 + __shfl_xor(t4, 4);
      v = v + __shfl_xor(v, 8);
      v = v + __shfl_xor(v, 16);
      v = v + __shfl_xor(v, 32);
      fin[c] = v;
    }
    if (ocg == 3){
      #pragma unroll
      for (int c = 0; c < 8; c++) sbuf[(r * 8 + c) * 16 + o] = fin[c];
    }
  }
  __syncthreads();

  // decode (verbatim verified arithmetic)
  if (t < 192){
    int a = t >> 6; int px = t & 63;
    int rr = px >> 3, cc = px & 7;
    int y = y0 + rr, x = x0 + cc;
    float img_f = (float)(*imgp);
    float sc = sbuf[px * 16 + a] + b_logits[a];
    float d0 = sbuf[px * 16 + 3 + a * 4 + 0] + b_reg[a * 4 + 0];
    float d1 = sbuf[px * 16 + 3 + a * 4 + 1] + b_reg[a * 4 + 1];
    float d2 = sbuf[px * 16 + 3 + a * 4 + 2] + b_reg[a * 4 + 2];
    float d3 = sbuf[px * 16 + 3 + a * 4 + 3] + b_reg[a * 4 + 3];
    double ar = (a == 0) ? 0.5 : ((a == 1) ? 1.0 : 2.0);
    double area_d = (double)ASIZE * (double)ASIZE;
    double wd = sqrt(area_d / ar);
    double hd = ar * wd;
    float bx1 = (float)(-wd * 0.5), by1 = (float)(-hd * 0.5);
    float bx2 = (float)( wd * 0.5), by2 = (float)( hd * 0.5);
    float sx = (float)(x * STRIDEV), sy = (float)(y * STRIDEV);
    float ax1 = sx + bx1, ay1 = sy + by1, ax2 = sx + bx2, ay2 = sy + by2;
    float aw = __fsub_rn(ax2, ax1), ah = __fsub_rn(ay2, ay1);
    float acx = __fadd_rn(ax1, __fmul_rn(0.5f, aw));
    float acy = __fadd_rn(ay1, __fmul_rn(0.5f, ah));
    const float CLAMP = (float)4.135166556742356;
    float dwv = fminf(d2, CLAMP), dhv = fminf(d3, CLAMP);
    float pcx = __fadd_rn(__fmul_rn(d0, aw), acx);
    float pcy = __fadd_rn(__fmul_rn(d1, ah), acy);
    float pw = __fmul_rn((float)exp((double)dwv), aw);
    float ph = __fmul_rn((float)exp((double)dhv), ah);
    float hx = __fmul_rn(0.5f, pw), hy = __fmul_rn(0.5f, ph);
    float X1 = __fsub_rn(pcx, hx), Y1 = __fsub_rn(pcy, hy);
    float X2 = __fadd_rn(pcx, hx), Y2 = __fadd_rn(pcy, hy);
    X1 = fminf(fmaxf(X1, 0.f), img_f); Y1 = fminf(fmaxf(Y1, 0.f), img_f);
    X2 = fminf(fmaxf(X2, 0.f), img_f); Y2 = fminf(fmaxf(Y2, 0.f), img_f);
    int gi = (y * W + x) * 3 + a;
    size_t oidx = (size_t)img * RTOT + FOFF + gi;
    score_base[oidx] = sc;
    ((float4*)box_base)[oidx] = make_float4(X1, Y1, X2, Y2);
  }
}

__global__ __launch_bounds__(512, 4) void conv_all(
    const float* __restrict__ f2, const float* __restrict__ f3,
    const float* __restrict__ f4, const float* __restrict__ f5,
    const float* __restrict__ f6, const float* __restrict__ w_r2,
    const float* __restrict__ zbuf,
    const float* __restrict__ b_inter, const float* __restrict__ w_logits,
    const float* __restrict__ b_logits, const float* __restrict__ w_reg,
    const float* __restrict__ b_reg, const int* __restrict__ imgp,
    float* __restrict__ score_base, float* __restrict__ box_base)
{
  __shared__ float lds_w[2 * 4608];
  __shared__ float lds_x[2 * 256];
  __shared__ float sbuf[64 * 16];
  const int bid = blockIdx.x;
  if (bid < 2048)
    conv_level<256, 4, 32, 0>(bid, f2, w_r2, zbuf, b_inter, w_logits, b_logits, w_reg,
                              b_reg, imgp, score_base, box_base, lds_w, lds_x, sbuf);
  else if (bid < 2560)
    conv_level<128, 8, 64, 196608>(bid - 2048, f3, w_r2, zbuf, b_inter, w_logits, b_logits,
                                   w_reg, b_reg, imgp, score_base, box_base, lds_w, lds_x, sbuf);
  else if (bid < 2688)
    conv_level<64, 16, 128, 245760>(bid - 2560, f4, w_r2, zbuf, b_inter, w_logits, b_logits,
                                    w_reg, b_reg, imgp, score_base, box_base, lds_w, lds_x, sbuf);
  else if (bid < 2720)
    conv_level<32, 32, 256, 258048>(bid - 2688, f5, w_r2, zbuf, b_inter, w_logits, b_logits,
                                    w_reg, b_reg, imgp, score_base, box_base, lds_w, lds_x, sbuf);
  else
    conv_level<16, 64, 512, 261120>(bid - 2720, f6, w_r2, zbuf, b_inter, w_logits, b_logits,
                                    w_reg, b_reg, imgp, score_base, box_base, lds_w, lds_x, sbuf);
}

// -------- kernel 2: per (level,image) exact top-k; per-wave private histograms --------
__global__ __launch_bounds__(1024) void topk_lvl(
    const float* __restrict__ score_base, const float* __restrict__ box_base,
    float* __restrict__ cs, float* __restrict__ cb, int* __restrict__ clvl)
{
  const int lvl = blockIdx.x, b = blockIdx.y;
  const int Rtab[5] = {196608, 49152, 12288, 3072, 768};
  const int Ktab[5] = {1000, 1000, 1000, 1000, 768};
  const int Ftab[5] = {0, 196608, 245760, 258048, 261120};
  const int Ctab[5] = {0, 1000, 2000, 3000, 4000};
  const int R = Rtab[lvl], kk = Ktab[lvl], foff = Ftab[lvl], coff = Ctab[lvl];
  const float* sc = score_base + (size_t)b * RTOT + foff;
  const int t = threadIdx.x;
  const int wv = t >> 6;
  __shared__ u32 histp[16 * 256];
  __shared__ u32 hist[256];
  __shared__ u32 sh_prefix, sh_r;
  __shared__ u32 cgt, ceq;
  __shared__ u64 sel[1024];
  __shared__ u64 eqb[1024];
  if (t == 0){ sh_prefix = 0u; sh_r = (u32)kk; }
  __syncthreads();
  for (int pass = 0; pass < 4; ++pass){
    for (int i = t; i < 4096; i += 1024) histp[i] = 0u;
    __syncthreads();
    u32 prefix = sh_prefix;
    int shift = 24 - 8 * pass;
    u32 maskHi = (pass == 0) ? 0u : (0xFFFFFFFFu << (shift + 8));
    for (int i = t; i < R; i += 1024){
      u32 key = fkey(sc[i]);
      if ((key & maskHi) == prefix) atomicAdd(&histp[wv * 256 + ((key >> shift) & 255u)], 1u);
    }
    __syncthreads();
    if (t < 256){
      u32 s = 0;
      #pragma unroll
      for (int w2 = 0; w2 < 16; w2++) s += histp[w2 * 256 + t];
      hist[t] = s;
    }
    __syncthreads();
    if (t == 0){
      u32 r = sh_r; u32 run = 0; int chosen = 255;
      for (int bv = 255; bv >= 0; --bv){
        u32 c = hist[bv];
        if (run + c >= r){ chosen = bv; break; }
        run += c;
      }
      sh_prefix = prefix | ((u32)chosen << shift);
      sh_r = r - run;
    }
    __syncthreads();
  }
  const u32 Tkey = sh_prefix; const u32 need_eq = sh_r;
  if (t == 0){ cgt = 0u; ceq = 0u; }
  __syncthreads();
  for (int i = t; i < R; i += 1024){
    u32 key = fkey(sc[i]);
    if (key > Tkey){
      u32 p = atomicAdd(&cgt, 1u);
      sel[p] = (((u64)key) << 32) | (u64)(0xFFFFFFFFu - (u32)i);
    } else if (key == Tkey){
      u32 e = atomicAdd(&ceq, 1u);
      if (e < 1024u) eqb[e] = (u64)(0xFFFFFFFFu - (u32)i);
    }
  }
  __syncthreads();
  u32 nGt = cgt; u32 nEq = ceq > 1024u ? 1024u : ceq;
  if ((u32)t >= nEq) eqb[t] = 0ull;
  __syncthreads();
  bitonic_desc(eqb, 1024, t, 1024);
  if ((u32)t < need_eq) sel[nGt + t] = (((u64)Tkey) << 32) | (eqb[t] & 0xFFFFFFFFull);
  if (t >= kk) sel[t] = 0ull;
  __syncthreads();
  bitonic_desc(sel, 1024, t, 1024);
  if (t < kk){
    u64 v = sel[t];
    u32 i = 0xFFFFFFFFu - (u32)(v & 0xFFFFFFFFull);
    int dst = b * TCAND + coff + t;
    cs[dst] = sc[i];
    ((float4*)cb)[dst] = ((const float4*)box_base)[(size_t)b * RTOT + foff + i];
    clvl[dst] = lvl;
  }
}

// -------- kernel 3: per-image global stable sort + NMS prep --------
__global__ __launch_bounds__(1024) void gsort(
    const float* __restrict__ cs, const float* __restrict__ cb, const int* __restrict__ clvl,
    const int* __restrict__ imgp,
    float* __restrict__ s_score, float* __restrict__ s_box, float* __restrict__ obox,
    float* __restrict__ area, int* __restrict__ validarr)
{
  const int b = blockIdx.x, t = threadIdx.x;
  __shared__ u64 arr[8192];
  for (int i = t; i < 8192; i += 1024){
    u64 v = 0ull;
    if (i < TCAND){
      u32 key = fkey(cs[b * TCAND + i]);
      v = (((u64)key) << 32) | (u64)(0xFFFFFFFFu - (u32)i);
    }
    arr[i] = v;
  }
  __syncthreads();
  bitonic_desc(arr, 8192, t, 1024);
  const float img = (float)(*imgp);
  const float off1 = img + 1.0f;
  for (int s = t; s < TCAND; s += 1024){
    u32 ci = 0xFFFFFFFFu - (u32)(arr[s] & 0xFFFFFFFFull);
    int src = b * TCAND + (int)ci;
    int dst = b * TCAND + s;
    float scv = cs[src];
    float4 bx = ((const float4*)cb)[src];
    s_score[dst] = scv;
    ((float4*)s_box)[dst] = bx;
    float lv = (float)clvl[src];
    float tt = __fmul_rn(lv, off1);
    float o0 = __fadd_rn(bx.x, tt), o1 = __fadd_rn(bx.y, tt);
    float o2 = __fadd_rn(bx.z, tt), o3 = __fadd_rn(bx.w, tt);
    ((float4*)obox)[dst] = make_float4(o0, o1, o2, o3);
    area[dst] = __fmul_rn(__fsub_rn(o2, o0), __fsub_rn(o3, o1));
    validarr[dst] = (bx.z > bx.x && bx.w > bx.y) ? 1 : 0;
  }
}

// -------- kernel 4: suppression bit-matrix; transposed mapping (i lane-fast) --------
// lanes: consecutive i, same w -> bi/area coalesced; bj/area[j] wave-uniform broadcast
__global__ void iou_mat(const float* __restrict__ obox, const float* __restrict__ area,
                        u64* __restrict__ supp)
{
  const int b = blockIdx.y;
  int wid = blockIdx.x * 256 + threadIdx.x;
  const int total = NW * TCAND;
  if (wid >= total) return;
  int w = wid / TCAND;
  int i = wid - w * TCAND;
  float4 bi = ((const float4*)obox)[b * TCAND + i];
  float ai = area[b * TCAND + i];
  u64 bits = 0ull;
  int jbase = w << 6;
  for (int jj = 0; jj < 64; jj++){
    int j = jbase + jj;
    if (j >= TCAND) break;
    if (j <= i) continue;
    float4 bj = ((const float4*)obox)[b * TCAND + j];
    float xx1 = fmaxf(bi.x, bj.x), yy1 = fmaxf(bi.y, bj.y);
    float xx2 = fminf(bi.z, bj.z), yy2 = fminf(bi.w, bj.w);
    float iw = fmaxf(__fsub_rn(xx2, xx1), 0.f);
    float ih = fmaxf(__fsub_rn(yy2, yy1), 0.f);
    float inter = __fmul_rn(iw, ih);
    float uni = __fadd_rn(__fsub_rn(__fadd_rn(ai, area[b * TCAND + j]), inter), 1e-9f);
    float iou = inter / uni;
    if (iou > 0.7f) bits |= (1ull << jj);
  }
  supp[((size_t)b * NROWS + i) * NW + w] = bits;
}

// -------- kernel 5: exact greedy scan; 4-way batched OR loads (bit-identical) --------
__global__ __launch_bounds__(64) void nms_scan(const u64* __restrict__ supp,
                                               const int* __restrict__ validarr,
                                               u64* __restrict__ keep_out)
{
  const int b = blockIdx.x;
  const int lane = threadIdx.x;
  u64 rlo = 0ull, rhi = 0ull;
  for (int jj = 0; jj < 64; jj++){
    int i1 = (lane << 6) + jj;
    u64 bad1 = (i1 < TCAND) ? (validarr[b * TCAND + i1] ? 0ull : 1ull) : 1ull;
    rlo |= bad1 << jj;
    int i2 = ((lane + 64) << 6) + jj;
    u64 bad2 = (i2 < TCAND) ? (validarr[b * TCAND + i2] ? 0ull : 1ull) : 1ull;
    rhi |= bad2 << jj;
  }
  for (int c = 0; c < NW; c++){
    u64 rw = (c < 64) ? __shfl(rlo, c) : __shfl(rhi, c - 64);
    u64 diag = supp[((size_t)b * NROWS + (c << 6) + lane) * NW + c];
    for (int s = 0; s < 64; s++){
      if (!((rw >> s) & 1ull)) rw |= __shfl(diag, s);
    }
    if (c < 64){ if (lane == c) rlo = rw; }
    else       { if (lane == c - 64) rhi = rw; }
    u64 kept = ~rw;
    const u64* rowbase = supp + ((size_t)b * NROWS + (c << 6)) * NW;
    // OR rows of kept entries; process 4 set bits per round (4 loads in flight).
    // OR is commutative/associative -> bit-identical to the sequential version.
    u64 rem = kept;
    while (rem){
      int s0 = (int)__builtin_ctzll(rem); rem &= rem - 1;
      int s1 = s0, s2 = s0, s3 = s0;
      if (rem){ s1 = (int)__builtin_ctzll(rem); rem &= rem - 1; }
      if (rem){ s2 = (int)__builtin_ctzll(rem); rem &= rem - 1; }
      if (rem){ s3 = (int)__builtin_ctzll(rem); rem &= rem - 1; }
      u64 a0 = rowbase[(size_t)s0 * NW + lane];
      u64 a1 = rowbase[(size_t)s1 * NW + lane];
      u64 a2 = rowbase[(size_t)s2 * NW + lane];
      u64 a3 = rowbase[(size_t)s3 * NW + lane];
      rlo |= (a0 | a1) | (a2 | a3);
      if (lane < 11){
        u64 h0 = rowbase[(size_t)s0 * NW + 64 + lane];
        u64 h1 = rowbase[(size_t)s1 * NW + 64 + lane];
        u64 h2 = rowbase[(size_t)s2 * NW + 64 + lane];
        u64 h3 = rowbase[(size_t)s3 * NW + 64 + lane];
        rhi |= (h0 | h1) | (h2 | h3);
      }
    }
  }
  keep_out[b * 80 + lane] = ~rlo;
  if (lane < 11) keep_out[b * 80 + 64 + lane] = ~rhi;
}

// -------- kernel 6: stable compaction + emit [B,1000,5] --------
__global__ __launch_bounds__(1024) void emit(const u64* __restrict__ keep_out,
                                             const float* __restrict__ s_score,
                                             const float* __restrict__ s_box,
                                             float* __restrict__ out)
{
  const int b = blockIdx.x, t = threadIdx.x;
  __shared__ int part[1024];
  int f[5]; int base = t * 5; int lsum = 0;
  #pragma unroll
  for (int q = 0; q < 5; q++){
    int s = base + q; int kp = 0;
    if (s < TCAND) kp = (int)((keep_out[b * 80 + (s >> 6)] >> (s & 63)) & 1ull);
    f[q] = kp; lsum += kp;
  }
  part[t] = lsum;
  __syncthreads();
  for (int d = 1; d < 1024; d <<= 1){
    int addv = 0;
    if (t >= d) addv = part[t - d];
    __syncthreads();
    part[t] += addv;
    __syncthreads();
  }
  int K = part[1023];
  int kcnt = part[t] - lsum;
  #pragma unroll
  for (int q = 0; q < 5; q++){
    int s = base + q;
    if (s < TCAND){
      int pos = f[q] ? kcnt : (K + (s - kcnt));
      if (pos < 1000){
        float4 bx = ((const float4*)s_box)[b * TCAND + s];
        float scv = f[q] ? s_score[b * TCAND + s] : NEGV;
        float* o = out + ((size_t)b * 1000 + pos) * 5;
        o[0] = bx.x; o[1] = bx.y; o[2] = bx.z; o[3] = bx.w; o[4] = scv;
      }
      kcnt += f[q];
    }
  }
}

extern "C" void kernel_launch(void* const* d_in, const int* in_sizes, int n_in,
                              void* d_out, int out_size, void* d_ws, size_t ws_size,
                              hipStream_t stream)
{
  (void)in_sizes; (void)n_in; (void)out_size; (void)ws_size;
  const float* f2 = (const float*)d_in[0];
  const float* f3 = (const float*)d_in[1];
  const float* f4 = (const float*)d_in[2];
  const float* f5 = (const float*)d_in[3];
  const float* f6 = (const float*)d_in[4];
  const float* w_inter  = (const float*)d_in[5];
  const float* b_inter  = (const float*)d_in[6];
  const float* w_logits = (const float*)d_in[7];
  const float* b_logits = (const float*)d_in[8];
  const float* w_reg    = (const float*)d_in[9];
  const float* b_reg    = (const float*)d_in[10];
  const int*   imgp     = (const int*)d_in[11];

  char* ws = (char*)d_ws;
  float* w_r2       = (float*)(ws + 0);          // 2,359,296
  float* score_base = (float*)(ws + 2359296);    // 2,095,104
  float* box_base   = (float*)(ws + 4454400);    // 8,380,416
  float* cs         = (float*)(ws + 12834816);   // 38,144
  float* cb         = (float*)(ws + 12872960);   // 152,576
  int*   clvl       = (int*)  (ws + 13025536);   // 38,144
  float* s_score    = (float*)(ws + 13063680);   // 38,144
  float* s_box      = (float*)(ws + 13101824);   // 152,576
  float* obox       = (float*)(ws + 13254400);   // 152,576
  float* area       = (float*)(ws + 13406976);   // 38,144
  int*   validarr   = (int*)  (ws + 13445120);   // 38,144
  u64*   supp       = (u64*)  (ws + 13483264);   // 5,760,000
  u64*   keep_out   = (u64*)  (ws + 19243264);   // 1,280
  float* zbuf       = (float*)(ws + 13483264);   // zero page (re-zeroed each launch)

  hipLaunchKernelGGL(wtrans, dim3((589824 + 255) / 256), dim3(256), 0, stream,
                     w_inter, w_r2, zbuf);

  hipLaunchKernelGGL(conv_all, dim3(2728), dim3(512), 0, stream,
                     f2, f3, f4, f5, f6, w_r2, zbuf, b_inter, w_logits, b_logits,
                     w_reg, b_reg, imgp, score_base, box_base);

  hipLaunchKernelGGL(topk_lvl, dim3(5, 2), dim3(1024), 0, stream,
                     score_base, box_base, cs, cb, clvl);
  hipLaunchKernelGGL(gsort, dim3(2), dim3(1024), 0, stream,
                     cs, cb, clvl, imgp, s_score, s_box, obox, area, validarr);
  hipLaunchKernelGGL(iou_mat, dim3((NW * TCAND + 255) / 256, 2), dim3(256), 0, stream,
                     obox, area, supp);
  hipLaunchKernelGGL(nms_scan, dim3(2), dim3(64), 0, stream, supp, validarr, keep_out);
  hipLaunchKernelGGL(emit, dim3(2), dim3(1024), 0, stream, keep_out, s_score, s_box,
                     (float*)d_out);
}

// Round 12
// 3862.806 us; speedup vs baseline: 1.2935x; 1.0350x over previous
//
#include <hip/hip_runtime.h>
#include <cmath>

typedef unsigned int u32;
typedef unsigned long long u64;

#define TCAND 4768
#define RTOT  261888
#define NW    75
#define NROWS 4800
#define NEGV  -1e9f

__device__ __forceinline__ u32 fkey(float s){
  u32 u = __float_as_uint(s);
  return u ^ ((u >> 31) ? 0xFFFFFFFFu : 0x80000000u);
}

// async global->LDS (lds base wave-uniform; HW adds lane*size; global addr per-lane)
__device__ __forceinline__ void gload_lds16(const float* g, float* l){
  __builtin_amdgcn_global_load_lds((const __attribute__((address_space(1))) void*)g,
                                   (__attribute__((address_space(3))) void*)l, 16, 0, 0);
}
__device__ __forceinline__ void gload_lds4(const float* g, float* l){
  __builtin_amdgcn_global_load_lds((const __attribute__((address_space(1))) void*)g,
                                   (__attribute__((address_space(3))) void*)l, 4, 0, 0);
}

// -------- descending bitonic sort of u64 in LDS (N power of two) --------
__device__ void bitonic_desc(u64* a, int N, int t, int nt){
  for (int len = 2; len <= N; len <<= 1){
    for (int inc = len >> 1; inc > 0; inc >>= 1){
      __syncthreads();
      for (int idx = t; idx < (N >> 1); idx += nt){
        int i = 2*idx - (idx & (inc - 1));
        int j = i + inc;
        u64 x = a[i], y = a[j];
        bool descR = ((i & len) == 0);
        bool sw = descR ? (x < y) : (x > y);
        if (sw){ a[i] = y; a[j] = x; }
      }
    }
  }
  __syncthreads();
}

// -------- kernel 0: weights -> w_r2[ic][tap][oc]; coalesced READ, scatter write --------
__global__ void wtrans(const float* __restrict__ w, float* __restrict__ w_r2,
                       float* __restrict__ zbuf){
  if (blockIdx.x == 0 && threadIdx.x < 16) zbuf[threadIdx.x] = 0.f;
  int idx = blockIdx.x * 256 + threadIdx.x;
  if (idx >= 589824) return;
  int oc = idx / 2304;
  int r  = idx - oc * 2304;
  int ic = r / 9;
  int tap = r - ic * 9;
  w_r2[ic * 2304 + tap * 256 + oc] = w[idx];
}

// -------- fused conv3x3 + heads + decode; 4oc x 8px per thread, 512 thr --------
// R9/R11 verified structure (BK=2, 2 LDS buffers, counted vmcnt, WAIT-THEN-BARRIER,
// launch_bounds (512,4)). Round-12 deltas: (a) sbuf aliases lds_w buffer 0 (dead
// after g=126's barrier) -> LDS 43008->38912 B -> 4 blocks/CU legal; (b) s_setprio(1)
// around the FMA region. Arithmetic byte-identical (absmax 0.0).
template<int H, int STRIDEV, int ASIZE, int FOFF>
__device__ __forceinline__ void conv_level(
    int rel, const float* __restrict__ feat, const float* __restrict__ w_r2,
    const float* __restrict__ zbuf,
    const float* __restrict__ b_inter, const float* __restrict__ w_logits,
    const float* __restrict__ b_logits, const float* __restrict__ w_reg,
    const float* __restrict__ b_reg, const int* __restrict__ imgp,
    float* __restrict__ score_base, float* __restrict__ box_base,
    float* lds_w, float* lds_x, float* sbuf)
{
  constexpr int W = H;
  constexpr int TX = H / 8;
  constexpr int TILES = TX * TX;
  const int t = threadIdx.x;
  const int img = rel / TILES;
  const int tile = rel - img * TILES;
  const int x0 = (tile % TX) << 3;
  const int y0 = (tile / TX) << 3;
  const int lane = t & 63;
  const int ocg = lane;          // oc = ocg*4 + k
  const int r = t >> 6;          // wave id = px row 0..7
  const int q = r;

  const size_t fb = (size_t)img * 256 * H * W;
  const size_t plane = (size_t)H * W;

  // per-lane x-cell source (waves 1,2 stage the 128-cell patch; pads/OOB -> zero page)
  const float* xsrc = zbuf;
  size_t xstep = 0;
  if (q == 1 || q == 2){
    int cell = (q - 1) * 64 + lane;
    int xr = cell / 12, xc = cell - xr * 12;
    int gy = y0 + xr - 1, gx = x0 + xc - 1;
    bool ok = (cell < 120) && (xc < 10) && gy >= 0 && gy < H && gx >= 0 && gx < W;
    if (ok){ xsrc = feat + fb + (size_t)gy * W + gx; xstep = plane; }
  }

  // weight chunk assignment for 18 chunks of 256 floats (2 ic = 4608 floats):
  const int c0 = 2 * q, c1 = 2 * q + 1;
  const int cex = (q == 0) ? 16 : ((q == 3) ? 17 : -1);

  float acc[32];
  #pragma unroll
  for (int j = 0; j < 32; j++) acc[j] = 0.f;

  #define STAGE(g_, sb) do { \
    const float* wg_ = w_r2 + (size_t)(g_) * 4608; \
    float* wl_ = lds_w + (sb) * 4608; \
    gload_lds16(wg_ + c0 * 256 + lane * 4, wl_ + c0 * 256); \
    gload_lds16(wg_ + c1 * 256 + lane * 4, wl_ + c1 * 256); \
    if (cex >= 0) gload_lds16(wg_ + cex * 256 + lane * 4, wl_ + cex * 256); \
    if (q == 1 || q == 2){ \
      gload_lds4(xsrc + (size_t)(2 * (g_)) * xstep, \
                 lds_x + (sb) * 256 + (q - 1) * 64); \
      gload_lds4(xsrc + (size_t)(2 * (g_) + 1) * xstep, \
                 lds_x + (sb) * 256 + 128 + (q - 1) * 64); \
    } \
  } while (0)

  STAGE(0, 0);

  int cur = 0;
  #pragma unroll 1
  for (int g = 0; g < 128; ++g){
    __builtin_amdgcn_s_barrier();
    __builtin_amdgcn_sched_barrier(0);
    if (g < 127){
      STAGE(g + 1, cur ^ 1);
    }
    __builtin_amdgcn_sched_barrier(0);
    if (g < 127){
      if (q == 1 || q == 2)      asm volatile("s_waitcnt vmcnt(4)" ::: "memory");
      else if (q == 0 || q == 3) asm volatile("s_waitcnt vmcnt(3)" ::: "memory");
      else                       asm volatile("s_waitcnt vmcnt(2)" ::: "memory");
    } else {
      asm volatile("s_waitcnt vmcnt(0)" ::: "memory");
    }
    __builtin_amdgcn_sched_barrier(0);
    __builtin_amdgcn_s_barrier();
    __builtin_amdgcn_sched_barrier(0);

    __builtin_amdgcn_s_setprio(1);
    const float* wbuf = lds_w + cur * 4608;
    const float* xbuf = lds_x + cur * 256;
    #pragma unroll 1
    for (int icl = 0; icl < 2; icl++){
      const float* wsub = wbuf + icl * 2304;
      const float* xsub = xbuf + icl * 128;
      #pragma unroll
      for (int ky = 0; ky < 3; ky++){
        float xrow[10];
        {
          const float* xp = xsub + (r + ky) * 12;
          *(float4*)&xrow[0] = *(const float4*)xp;
          *(float4*)&xrow[4] = *(const float4*)(xp + 4);
          *(float2*)&xrow[8] = *(const float2*)(xp + 8);
        }
        #pragma unroll
        for (int kx = 0; kx < 3; kx++){
          const int tap = ky * 3 + kx;
          float wk[4];
          *(float4*)&wk[0] = *(const float4*)(wsub + tap * 256 + ocg * 4);
          #pragma unroll
          for (int k = 0; k < 4; k++){
            #pragma unroll
            for (int c = 0; c < 8; c++)
              acc[k * 8 + c] = __builtin_fmaf(wk[k], xrow[c + kx], acc[k * 8 + c]);
          }
        }
      }
    }
    __builtin_amdgcn_s_setprio(0);
    cur ^= 1;
  }
  #undef STAGE

  // bias + relu in place (oc = ocg*4 + k)
  {
    float bb[4];
    *(float4*)&bb[0] = *(const float4*)(b_inter + ocg * 4);
    #pragma unroll
    for (int k = 0; k < 4; k++)
      #pragma unroll
      for (int c = 0; c < 8; c++)
        acc[k * 8 + c] = fmaxf(acc[k * 8 + c] + bb[k], 0.f);
  }

  // heads: exact 16-chain + xor butterfly tree (bit-exact, verified)
  // sbuf aliases lds_w[0..1023] (buffer 0) — dead for reads since g=126's barrier;
  // any straggler wave in g=127 reads only buffer 1 (floats 4608+), disjoint.
  const int grp = ocg & 60;
  #pragma unroll 1
  for (int o = 0; o < 15; o++){
    const float* whp = (o < 3) ? (w_logits + o * 256) : (w_reg + (o - 3) * 256);
    float wh4[4];
    *(float4*)&wh4[0] = *(const float4*)(whp + ocg * 4);
    float fin[8];
    #pragma unroll
    for (int c = 0; c < 8; c++){
      float t1 = 0.f;
      #pragma unroll
      for (int k = 0; k < 4; k++) t1 = __builtin_fmaf(wh4[k], acc[k * 8 + c], t1);
      float b1 = __shfl(t1, grp);
      float t2 = b1;
      #pragma unroll
      for (int k = 0; k < 4; k++) t2 = __builtin_fmaf(wh4[k], acc[k * 8 + c], t2);
      float b2 = __shfl(t2, grp + 1);
      float t3 = b2;
      #pragma unroll
      for (int k = 0; k < 4; k++) t3 = __builtin_fmaf(wh4[k], acc[k * 8 + c], t3);
      float b3 = __shfl(t3, grp + 2);
      float t4 = b3;
      #pragma unroll
      for (int k = 0; k < 4; k++) t4 = __builtin_fmaf(wh4[k], acc[k * 8 + c], t4);
      float v = t4 + __shfl_xor(t4, 4);
      v = v + __shfl_xor(v, 8);
      v = v + __shfl_xor(v, 16);
      v = v + __shfl_xor(v, 32);
      fin[c] = v;
    }
    if (ocg == 3){
      #pragma unroll
      for (int c = 0; c < 8; c++) sbuf[(r * 8 + c) * 16 + o] = fin[c];
    }
  }
  __syncthreads();

  // decode (verbatim verified arithmetic)
  if (t < 192){
    int a = t >> 6; int px = t & 63;
    int rr = px >> 3, cc = px & 7;
    int y = y0 + rr, x = x0 + cc;
    float img_f = (float)(*imgp);
    float sc = sbuf[px * 16 + a] + b_logits[a];
    float d0 = sbuf[px * 16 + 3 + a * 4 + 0] + b_reg[a * 4 + 0];
    float d1 = sbuf[px * 16 + 3 + a * 4 + 1] + b_reg[a * 4 + 1];
    float d2 = sbuf[px * 16 + 3 + a * 4 + 2] + b_reg[a * 4 + 2];
    float d3 = sbuf[px * 16 + 3 + a * 4 + 3] + b_reg[a * 4 + 3];
    double ar = (a == 0) ? 0.5 : ((a == 1) ? 1.0 : 2.0);
    double area_d = (double)ASIZE * (double)ASIZE;
    double wd = sqrt(area_d / ar);
    double hd = ar * wd;
    float bx1 = (float)(-wd * 0.5), by1 = (float)(-hd * 0.5);
    float bx2 = (float)( wd * 0.5), by2 = (float)( hd * 0.5);
    float sx = (float)(x * STRIDEV), sy = (float)(y * STRIDEV);
    float ax1 = sx + bx1, ay1 = sy + by1, ax2 = sx + bx2, ay2 = sy + by2;
    float aw = __fsub_rn(ax2, ax1), ah = __fsub_rn(ay2, ay1);
    float acx = __fadd_rn(ax1, __fmul_rn(0.5f, aw));
    float acy = __fadd_rn(ay1, __fmul_rn(0.5f, ah));
    const float CLAMP = (float)4.135166556742356;
    float dwv = fminf(d2, CLAMP), dhv = fminf(d3, CLAMP);
    float pcx = __fadd_rn(__fmul_rn(d0, aw), acx);
    float pcy = __fadd_rn(__fmul_rn(d1, ah), acy);
    float pw = __fmul_rn((float)exp((double)dwv), aw);
    float ph = __fmul_rn((float)exp((double)dhv), ah);
    float hx = __fmul_rn(0.5f, pw), hy = __fmul_rn(0.5f, ph);
    float X1 = __fsub_rn(pcx, hx), Y1 = __fsub_rn(pcy, hy);
    float X2 = __fadd_rn(pcx, hx), Y2 = __fadd_rn(pcy, hy);
    X1 = fminf(fmaxf(X1, 0.f), img_f); Y1 = fminf(fmaxf(Y1, 0.f), img_f);
    X2 = fminf(fmaxf(X2, 0.f), img_f); Y2 = fminf(fmaxf(Y2, 0.f), img_f);
    int gi = (y * W + x) * 3 + a;
    size_t oidx = (size_t)img * RTOT + FOFF + gi;
    score_base[oidx] = sc;
    ((float4*)box_base)[oidx] = make_float4(X1, Y1, X2, Y2);
  }
}

__global__ __launch_bounds__(512, 4) void conv_all(
    const float* __restrict__ f2, const float* __restrict__ f3,
    const float* __restrict__ f4, const float* __restrict__ f5,
    const float* __restrict__ f6, const float* __restrict__ w_r2,
    const float* __restrict__ zbuf,
    const float* __restrict__ b_inter, const float* __restrict__ w_logits,
    const float* __restrict__ b_logits, const float* __restrict__ w_reg,
    const float* __restrict__ b_reg, const int* __restrict__ imgp,
    float* __restrict__ score_base, float* __restrict__ box_base)
{
  __shared__ float lds_w[2 * 4608];   // sbuf aliases lds_w[0..1023]
  __shared__ float lds_x[2 * 256];
  float* sbuf = lds_w;
  const int bid = blockIdx.x;
  if (bid < 2048)
    conv_level<256, 4, 32, 0>(bid, f2, w_r2, zbuf, b_inter, w_logits, b_logits, w_reg,
                              b_reg, imgp, score_base, box_base, lds_w, lds_x, sbuf);
  else if (bid < 2560)
    conv_level<128, 8, 64, 196608>(bid - 2048, f3, w_r2, zbuf, b_inter, w_logits, b_logits,
                                   w_reg, b_reg, imgp, score_base, box_base, lds_w, lds_x, sbuf);
  else if (bid < 2688)
    conv_level<64, 16, 128, 245760>(bid - 2560, f4, w_r2, zbuf, b_inter, w_logits, b_logits,
                                    w_reg, b_reg, imgp, score_base, box_base, lds_w, lds_x, sbuf);
  else if (bid < 2720)
    conv_level<32, 32, 256, 258048>(bid - 2688, f5, w_r2, zbuf, b_inter, w_logits, b_logits,
                                    w_reg, b_reg, imgp, score_base, box_base, lds_w, lds_x, sbuf);
  else
    conv_level<16, 64, 512, 261120>(bid - 2720, f6, w_r2, zbuf, b_inter, w_logits, b_logits,
                                    w_reg, b_reg, imgp, score_base, box_base, lds_w, lds_x, sbuf);
}

// -------- kernel 2: per (level,image) exact top-k; per-wave private histograms --------
__global__ __launch_bounds__(1024) void topk_lvl(
    const float* __restrict__ score_base, const float* __restrict__ box_base,
    float* __restrict__ cs, float* __restrict__ cb, int* __restrict__ clvl)
{
  const int lvl = blockIdx.x, b = blockIdx.y;
  const int Rtab[5] = {196608, 49152, 12288, 3072, 768};
  const int Ktab[5] = {1000, 1000, 1000, 1000, 768};
  const int Ftab[5] = {0, 196608, 245760, 258048, 261120};
  const int Ctab[5] = {0, 1000, 2000, 3000, 4000};
  const int R = Rtab[lvl], kk = Ktab[lvl], foff = Ftab[lvl], coff = Ctab[lvl];
  const float* sc = score_base + (size_t)b * RTOT + foff;
  const int t = threadIdx.x;
  const int wv = t >> 6;
  __shared__ u32 histp[16 * 256];
  __shared__ u32 hist[256];
  __shared__ u32 sh_prefix, sh_r;
  __shared__ u32 cgt, ceq;
  __shared__ u64 sel[1024];
  __shared__ u64 eqb[1024];
  if (t == 0){ sh_prefix = 0u; sh_r = (u32)kk; }
  __syncthreads();
  for (int pass = 0; pass < 4; ++pass){
    for (int i = t; i < 4096; i += 1024) histp[i] = 0u;
    __syncthreads();
    u32 prefix = sh_prefix;
    int shift = 24 - 8 * pass;
    u32 maskHi = (pass == 0) ? 0u : (0xFFFFFFFFu << (shift + 8));
    for (int i = t; i < R; i += 1024){
      u32 key = fkey(sc[i]);
      if ((key & maskHi) == prefix) atomicAdd(&histp[wv * 256 + ((key >> shift) & 255u)], 1u);
    }
    __syncthreads();
    if (t < 256){
      u32 s = 0;
      #pragma unroll
      for (int w2 = 0; w2 < 16; w2++) s += histp[w2 * 256 + t];
      hist[t] = s;
    }
    __syncthreads();
    if (t == 0){
      u32 r = sh_r; u32 run = 0; int chosen = 255;
      for (int bv = 255; bv >= 0; --bv){
        u32 c = hist[bv];
        if (run + c >= r){ chosen = bv; break; }
        run += c;
      }
      sh_prefix = prefix | ((u32)chosen << shift);
      sh_r = r - run;
    }
    __syncthreads();
  }
  const u32 Tkey = sh_prefix; const u32 need_eq = sh_r;
  if (t == 0){ cgt = 0u; ceq = 0u; }
  __syncthreads();
  for (int i = t; i < R; i += 1024){
    u32 key = fkey(sc[i]);
    if (key > Tkey){
      u32 p = atomicAdd(&cgt, 1u);
      sel[p] = (((u64)key) << 32) | (u64)(0xFFFFFFFFu - (u32)i);
    } else if (key == Tkey){
      u32 e = atomicAdd(&ceq, 1u);
      if (e < 1024u) eqb[e] = (u64)(0xFFFFFFFFu - (u32)i);
    }
  }
  __syncthreads();
  u32 nGt = cgt; u32 nEq = ceq > 1024u ? 1024u : ceq;
  if ((u32)t >= nEq) eqb[t] = 0ull;
  __syncthreads();
  bitonic_desc(eqb, 1024, t, 1024);
  if ((u32)t < need_eq) sel[nGt + t] = (((u64)Tkey) << 32) | (eqb[t] & 0xFFFFFFFFull);
  if (t >= kk) sel[t] = 0ull;
  __syncthreads();
  bitonic_desc(sel, 1024, t, 1024);
  if (t < kk){
    u64 v = sel[t];
    u32 i = 0xFFFFFFFFu - (u32)(v & 0xFFFFFFFFull);
    int dst = b * TCAND + coff + t;
    cs[dst] = sc[i];
    ((float4*)cb)[dst] = ((const float4*)box_base)[(size_t)b * RTOT + foff + i];
    clvl[dst] = lvl;
  }
}

// -------- kernel 3: per-image global stable sort + NMS prep --------
__global__ __launch_bounds__(1024) void gsort(
    const float* __restrict__ cs, const float* __restrict__ cb, const int* __restrict__ clvl,
    const int* __restrict__ imgp,
    float* __restrict__ s_score, float* __restrict__ s_box, float* __restrict__ obox,
    float* __restrict__ area, int* __restrict__ validarr)
{
  const int b = blockIdx.x, t = threadIdx.x;
  __shared__ u64 arr[8192];
  for (int i = t; i < 8192; i += 1024){
    u64 v = 0ull;
    if (i < TCAND){
      u32 key = fkey(cs[b * TCAND + i]);
      v = (((u64)key) << 32) | (u64)(0xFFFFFFFFu - (u32)i);
    }
    arr[i] = v;
  }
  __syncthreads();
  bitonic_desc(arr, 8192, t, 1024);
  const float img = (float)(*imgp);
  const float off1 = img + 1.0f;
  for (int s = t; s < TCAND; s += 1024){
    u32 ci = 0xFFFFFFFFu - (u32)(arr[s] & 0xFFFFFFFFull);
    int src = b * TCAND + (int)ci;
    int dst = b * TCAND + s;
    float scv = cs[src];
    float4 bx = ((const float4*)cb)[src];
    s_score[dst] = scv;
    ((float4*)s_box)[dst] = bx;
    float lv = (float)clvl[src];
    float tt = __fmul_rn(lv, off1);
    float o0 = __fadd_rn(bx.x, tt), o1 = __fadd_rn(bx.y, tt);
    float o2 = __fadd_rn(bx.z, tt), o3 = __fadd_rn(bx.w, tt);
    ((float4*)obox)[dst] = make_float4(o0, o1, o2, o3);
    area[dst] = __fmul_rn(__fsub_rn(o2, o0), __fsub_rn(o3, o1));
    validarr[dst] = (bx.z > bx.x && bx.w > bx.y) ? 1 : 0;
  }
}

// -------- kernel 4: suppression bit-matrix; transposed mapping (i lane-fast) --------
__global__ void iou_mat(const float* __restrict__ obox, const float* __restrict__ area,
                        u64* __restrict__ supp)
{
  const int b = blockIdx.y;
  int wid = blockIdx.x * 256 + threadIdx.x;
  const int total = NW * TCAND;
  if (wid >= total) return;
  int w = wid / TCAND;
  int i = wid - w * TCAND;
  float4 bi = ((const float4*)obox)[b * TCAND + i];
  float ai = area[b * TCAND + i];
  u64 bits = 0ull;
  int jbase = w << 6;
  for (int jj = 0; jj < 64; jj++){
    int j = jbase + jj;
    if (j >= TCAND) break;
    if (j <= i) continue;
    float4 bj = ((const float4*)obox)[b * TCAND + j];
    float xx1 = fmaxf(bi.x, bj.x), yy1 = fmaxf(bi.y, bj.y);
    float xx2 = fminf(bi.z, bj.z), yy2 = fminf(bi.w, bj.w);
    float iw = fmaxf(__fsub_rn(xx2, xx1), 0.f);
    float ih = fmaxf(__fsub_rn(yy2, yy1), 0.f);
    float inter = __fmul_rn(iw, ih);
    float uni = __fadd_rn(__fsub_rn(__fadd_rn(ai, area[b * TCAND + j]), inter), 1e-9f);
    float iou = inter / uni;
    if (iou > 0.7f) bits |= (1ull << jj);
  }
  supp[((size_t)b * NROWS + i) * NW + w] = bits;
}

// -------- kernel 5: exact greedy scan; 4-way batched OR loads (bit-identical) --------
__global__ __launch_bounds__(64) void nms_scan(const u64* __restrict__ supp,
                                               const int* __restrict__ validarr,
                                               u64* __restrict__ keep_out)
{
  const int b = blockIdx.x;
  const int lane = threadIdx.x;
  u64 rlo = 0ull, rhi = 0ull;
  for (int jj = 0; jj < 64; jj++){
    int i1 = (lane << 6) + jj;
    u64 bad1 = (i1 < TCAND) ? (validarr[b * TCAND + i1] ? 0ull : 1ull) : 1ull;
    rlo |= bad1 << jj;
    int i2 = ((lane + 64) << 6) + jj;
    u64 bad2 = (i2 < TCAND) ? (validarr[b * TCAND + i2] ? 0ull : 1ull) : 1ull;
    rhi |= bad2 << jj;
  }
  for (int c = 0; c < NW; c++){
    u64 rw = (c < 64) ? __shfl(rlo, c) : __shfl(rhi, c - 64);
    u64 diag = supp[((size_t)b * NROWS + (c << 6) + lane) * NW + c];
    for (int s = 0; s < 64; s++){
      if (!((rw >> s) & 1ull)) rw |= __shfl(diag, s);
    }
    if (c < 64){ if (lane == c) rlo = rw; }
    else       { if (lane == c - 64) rhi = rw; }
    u64 kept = ~rw;
    const u64* rowbase = supp + ((size_t)b * NROWS + (c << 6)) * NW;
    u64 rem = kept;
    while (rem){
      int s0 = (int)__builtin_ctzll(rem); rem &= rem - 1;
      int s1 = s0, s2 = s0, s3 = s0;
      if (rem){ s1 = (int)__builtin_ctzll(rem); rem &= rem - 1; }
      if (rem){ s2 = (int)__builtin_ctzll(rem); rem &= rem - 1; }
      if (rem){ s3 = (int)__builtin_ctzll(rem); rem &= rem - 1; }
      u64 a0 = rowbase[(size_t)s0 * NW + lane];
      u64 a1 = rowbase[(size_t)s1 * NW + lane];
      u64 a2 = rowbase[(size_t)s2 * NW + lane];
      u64 a3 = rowbase[(size_t)s3 * NW + lane];
      rlo |= (a0 | a1) | (a2 | a3);
      if (lane < 11){
        u64 h0 = rowbase[(size_t)s0 * NW + 64 + lane];
        u64 h1 = rowbase[(size_t)s1 * NW + 64 + lane];
        u64 h2 = rowbase[(size_t)s2 * NW + 64 + lane];
        u64 h3 = rowbase[(size_t)s3 * NW + 64 + lane];
        rhi |= (h0 | h1) | (h2 | h3);
      }
    }
  }
  keep_out[b * 80 + lane] = ~rlo;
  if (lane < 11) keep_out[b * 80 + 64 + lane] = ~rhi;
}

// -------- kernel 6: stable compaction + emit [B,1000,5] --------
__global__ __launch_bounds__(1024) void emit(const u64* __restrict__ keep_out,
                                             const float* __restrict__ s_score,
                                             const float* __restrict__ s_box,
                                             float* __restrict__ out)
{
  const int b = blockIdx.x, t = threadIdx.x;
  __shared__ int part[1024];
  int f[5]; int base = t * 5; int lsum = 0;
  #pragma unroll
  for (int q = 0; q < 5; q++){
    int s = base + q; int kp = 0;
    if (s < TCAND) kp = (int)((keep_out[b * 80 + (s >> 6)] >> (s & 63)) & 1ull);
    f[q] = kp; lsum += kp;
  }
  part[t] = lsum;
  __syncthreads();
  for (int d = 1; d < 1024; d <<= 1){
    int addv = 0;
    if (t >= d) addv = part[t - d];
    __syncthreads();
    part[t] += addv;
    __syncthreads();
  }
  int K = part[1023];
  int kcnt = part[t] - lsum;
  #pragma unroll
  for (int q = 0; q < 5; q++){
    int s = base + q;
    if (s < TCAND){
      int pos = f[q] ? kcnt : (K + (s - kcnt));
      if (pos < 1000){
        float4 bx = ((const float4*)s_box)[b * TCAND + s];
        float scv = f[q] ? s_score[b * TCAND + s] : NEGV;
        float* o = out + ((size_t)b * 1000 + pos) * 5;
        o[0] = bx.x; o[1] = bx.y; o[2] = bx.z; o[3] = bx.w; o[4] = scv;
      }
      kcnt += f[q];
    }
  }
}

extern "C" void kernel_launch(void* const* d_in, const int* in_sizes, int n_in,
                              void* d_out, int out_size, void* d_ws, size_t ws_size,
                              hipStream_t stream)
{
  (void)in_sizes; (void)n_in; (void)out_size; (void)ws_size;
  const float* f2 = (const float*)d_in[0];
  const float* f3 = (const float*)d_in[1];
  const float* f4 = (const float*)d_in[2];
  const float* f5 = (const float*)d_in[3];
  const float* f6 = (const float*)d_in[4];
  const float* w_inter  = (const float*)d_in[5];
  const float* b_inter  = (const float*)d_in[6];
  const float* w_logits = (const float*)d_in[7];
  const float* b_logits = (const float*)d_in[8];
  const float* w_reg    = (const float*)d_in[9];
  const float* b_reg    = (const float*)d_in[10];
  const int*   imgp     = (const int*)d_in[11];

  char* ws = (char*)d_ws;
  float* w_r2       = (float*)(ws + 0);          // 2,359,296
  float* score_base = (float*)(ws + 2359296);    // 2,095,104
  float* box_base   = (float*)(ws + 4454400);    // 8,380,416
  float* cs         = (float*)(ws + 12834816);   // 38,144
  float* cb         = (float*)(ws + 12872960);   // 152,576
  int*   clvl       = (int*)  (ws + 13025536);   // 38,144
  float* s_score    = (float*)(ws + 13063680);   // 38,144
  float* s_box      = (float*)(ws + 13101824);   // 152,576
  float* obox       = (float*)(ws + 13254400);   // 152,576
  float* area       = (float*)(ws + 13406976);   // 38,144
  int*   validarr   = (int*)  (ws + 13445120);   // 38,144
  u64*   supp       = (u64*)  (ws + 13483264);   // 5,760,000
  u64*   keep_out   = (u64*)  (ws + 19243264);   // 1,280
  float* zbuf       = (float*)(ws + 13483264);   // zero page (re-zeroed each launch)

  hipLaunchKernelGGL(wtrans, dim3((589824 + 255) / 256), dim3(256), 0, stream,
                     w_inter, w_r2, zbuf);

  hipLaunchKernelGGL(conv_all, dim3(2728), dim3(512), 0, stream,
                     f2, f3, f4, f5, f6, w_r2, zbuf, b_inter, w_logits, b_logits,
                     w_reg, b_reg, imgp, score_base, box_base);

  hipLaunchKernelGGL(topk_lvl, dim3(5, 2), dim3(1024), 0, stream,
                     score_base, box_base, cs, cb, clvl);
  hipLaunchKernelGGL(gsort, dim3(2), dim3(1024), 0, stream,
                     cs, cb, clvl, imgp, s_score, s_box, obox, area, validarr);
  hipLaunchKernelGGL(iou_mat, dim3((NW * TCAND + 255) / 256, 2), dim3(256), 0, stream,
                     obox, area, supp);
  hipLaunchKernelGGL(nms_scan, dim3(2), dim3(64), 0, stream, supp, validarr, keep_out);
  hipLaunchKernelGGL(emit, dim3(2), dim3(1024), 0, stream, keep_out, s_score, s_box,
                     (float*)d_out);
}